// Round 4
// baseline (7867.391 us; speedup 1.0000x reference)
//
#include <hip/hip_runtime.h>
#include <hip/hip_bf16.h>

#define T_STEPS 512
#define BATCH 64
#define TB (T_STEPS * BATCH)   // 32768
#define HPAD 260

typedef short bf16x8 __attribute__((ext_vector_type(8)));
typedef float f32x4 __attribute__((ext_vector_type(4)));

union FragU { uint4 u; bf16x8 v; };

static __device__ __forceinline__ bf16x8 ld_frag(const uint4* p) {
  FragU f; f.u = *p; return f.v;
}

static __device__ __forceinline__ unsigned short f2bf(float f) {
  unsigned u = __float_as_uint(f);
  return (unsigned short)((u + 0x7FFFu + ((u >> 16) & 1u)) >> 16);
}

static __device__ __forceinline__ int revrow(int r) {
  int t = r >> 6, b = r & 63;
  return ((T_STEPS - 1 - t) << 6) | b;
}

#define S_RZ  (-1.4426950408889634f)   /* -log2(e)   : sigmoid(p)=1/(1+2^(S_RZ*p)) */
#define S_C   (-2.8853900817779268f)   /* -2*log2(e) : tanh(p)=2/(1+2^(S_C*p))-1   */

// ---------------- pack weights into MFMA B-fragment layout (with gate pre-scaling) ----
// modes: 0 = X3 (768 cols, order [r|cand|z], g=n>>8), 1 = RZ (512 cols, g=n<256?0:2), 2 = C (256 cols, g=1)
__global__ void pack_w_kernel(const float* __restrict__ W, int rows, int k_base,
                              int n_tiles, int k_tiles, int mode,
                              unsigned short* __restrict__ dst) {
  int gid = blockIdx.x * blockDim.x + threadIdx.x;
  int total = n_tiles * k_tiles * 64;
  if (gid >= total) return;
  int lane = gid & 63;
  int fi = gid >> 6;
  int kt = fi % k_tiles;
  int nt = fi / k_tiles;
  int n = nt * 16 + (lane & 15);
  int g, col; float s;
  if (mode == 0)      { g = n >> 8;            col = n & 255; s = (g == 1) ? S_C : S_RZ; }
  else if (mode == 1) { g = (n < 256) ? 0 : 2; col = n & 255; s = S_RZ; }
  else                { g = 1;                 col = n;       s = S_C; }
  int k0 = k_base + kt * 32 + ((lane >> 4) << 3);
  const float* src = W + ((size_t)g * rows + k0) * 256 + col;
  unsigned short v[8];
#pragma unroll
  for (int j = 0; j < 8; ++j) v[j] = f2bf(src[(size_t)j * 256] * s);
  uint4 o;
  o.x = v[0] | ((unsigned)v[1] << 16);
  o.y = v[2] | ((unsigned)v[3] << 16);
  o.z = v[4] | ((unsigned)v[5] << 16);
  o.w = v[6] | ((unsigned)v[7] << 16);
  ((uint4*)dst)[gid] = o;
}

static __device__ __forceinline__ bf16x8 cvt8(float4 f0, float4 f1) {
  uint4 o;
  o.x = f2bf(f0.x) | ((unsigned)f2bf(f0.y) << 16);
  o.y = f2bf(f0.z) | ((unsigned)f2bf(f0.w) << 16);
  o.z = f2bf(f1.x) | ((unsigned)f2bf(f1.y) << 16);
  o.w = f2bf(f1.z) | ((unsigned)f2bf(f1.w) << 16);
  FragU f; f.u = o; return f.v;
}

// ---------------- Xg GEMM (chunked): writes C-fragment tile layout --------------------
// Xg per dir: [rt = chunkT*4][ct = 48][lane = 64] f32x4  (16-row C tile per (rt,ct))
//   lane mapping: col = ct*16 + (lane&15), row_in_tile = (lane>>4)*4 + reg
template<int LAYER>
__global__ __launch_bounds__(256)
void gemm_xg_kernel(const float* __restrict__ x,
                    const unsigned short* __restrict__ fs0,
                    const unsigned short* __restrict__ bs0,
                    const unsigned short* __restrict__ Bp,
                    const float* __restrict__ bias_fw,
                    const float* __restrict__ bias_bw,
                    f32x4* __restrict__ Xg, int t0, int chunkT)
{
  constexpr int KT = (LAYER == 0) ? 8 : 16;
  int dir = blockIdx.z;
  int lane = threadIdx.x & 63;
  int w = threadIdx.x >> 6;
  int ww = w >> 1, wc = w & 1;
  int mt0 = blockIdx.x * 8 + ww * 4;
  int nt0 = blockIdx.y * 8 + wc * 4;
  const uint4* B = (const uint4*)Bp + (size_t)dir * 48 * KT * 64;
  const int arow = lane & 15;
  const int k0b = ((lane >> 4) << 3);

  f32x4 acc[4][4] = {};
#pragma unroll
  for (int kt = 0; kt < KT; ++kt) {
    int k0 = kt * 32 + k0b;
    bf16x8 a[4], b[4];
#pragma unroll
    for (int i = 0; i < 4; ++i) {
      int grow = t0 * 64 + (mt0 + i) * 16 + arow;
      if (LAYER == 0) {
        int gr = dir ? revrow(grow) : grow;
        const float4* s = (const float4*)(x + (size_t)gr * 256 + k0);
        a[i] = cvt8(s[0], s[1]);
      } else {
        const unsigned short* base; int r2 = grow, kk = k0;
        if (k0 < 256) { base = dir ? bs0 : fs0; }
        else          { base = dir ? fs0 : bs0; r2 = revrow(grow); kk = k0 - 256; }
        a[i] = *(const bf16x8*)(base + (size_t)r2 * 256 + kk);
      }
    }
#pragma unroll
    for (int j = 0; j < 4; ++j) b[j] = ld_frag(B + ((size_t)(nt0 + j) * KT + kt) * 64 + lane);
#pragma unroll
    for (int i = 0; i < 4; ++i)
#pragma unroll
      for (int j = 0; j < 4; ++j)
        acc[i][j] = __builtin_amdgcn_mfma_f32_16x16x32_bf16(a[i], b[j], acc[i][j], 0, 0, 0);
  }

  const float* bias = dir ? bias_bw : bias_fw;
  f32x4* C = Xg + (size_t)dir * (chunkT * 4) * 48 * 64;
#pragma unroll
  for (int j = 0; j < 4; ++j) {
    int ct = nt0 + j;
    int col = ct * 16 + (lane & 15);
    int g = col >> 8, cc = col & 255;
    float bv = ((g == 1) ? S_C : S_RZ) * bias[g * 256 + cc];
#pragma unroll
    for (int i = 0; i < 4; ++i) {
      int rt = blockIdx.x * 8 + ww * 4 + i;        // chunk-local 16-row tile index
      f32x4 v = acc[i][j];
      v[0] += bv; v[1] += bv; v[2] += bv; v[3] += bv;
      C[((size_t)rt * 48 + ct) * 64 + lane] = v;
    }
  }
}

// ---------------- persistent recurrent GRU kernel (one layer, both dirs, chunked) -----
// grid (4, 2): blockIdx.x = 16-row batch block, blockIdx.y = dir. 1024 threads = 16 waves.
// Per-wave weights: 2 rz-ntiles + 1 cand-ntile = 96 VGPRs -> fits the 128-VGPR cap.
template<int LAYER>
__global__ __launch_bounds__(1024)
void gru_kernel(const f32x4* __restrict__ Xg,
                const uint4* __restrict__ whrz_fw, const uint4* __restrict__ whrz_bw, // [32][8][64]
                const uint4* __restrict__ whc_fw,  const uint4* __restrict__ whc_bw,  // [16][8][64]
                unsigned short* __restrict__ sfw_bf, unsigned short* __restrict__ sbw_bf,
                float* __restrict__ out,
                float* __restrict__ hstate, float* __restrict__ dout_h,
                int t0, int chunkT)
{
  const int dir = blockIdx.y;
  const int bx = blockIdx.x;
  const int row0 = bx * 16;
  const int tid = threadIdx.x;
  const int lane = tid & 63;
  const int w = tid >> 6;               // 0..15

  __shared__ __align__(16) unsigned short h_bf[16 * 256];   // swizzled bf16 h
  __shared__ __align__(16) unsigned short rh_bf[16 * 256];  // swizzled bf16 r*h
  __shared__ __align__(16) float h_f[16 * HPAD];            // fp32 h (padded stride)
  __shared__ __align__(16) float z_f[16 * HPAD];            // fp32 z gate

  const uint4* whrzp = dir ? whrz_bw : whrz_fw;
  const uint4* whcp  = dir ? whc_bw  : whc_fw;

  // resident weights: wave w owns rz ntiles q0=2w,2w+1 and cand ntile w  (96 VGPRs)
  bf16x8 wrz[2][8], whcf[8];
#pragma unroll
  for (int j = 0; j < 2; ++j)
#pragma unroll
    for (int kt = 0; kt < 8; ++kt)
      wrz[j][kt] = ld_frag(whrzp + ((size_t)(w * 2 + j) * 8 + kt) * 64 + lane);
#pragma unroll
  for (int kt = 0; kt < 8; ++kt)
    whcf[kt] = ld_frag(whcp + ((size_t)w * 8 + kt) * 64 + lane);

  float* hst = hstate + (size_t)(dir * 4 + bx) * 4096;
  for (int i = tid; i < 16 * 256; i += 1024) {
    float v = (t0 == 0) ? 0.0f : hst[i];
    int rr = i >> 8, cc = i & 255;
    h_f[rr * HPAD + cc] = v;
    int cb = cc * 2;
    int byt = rr * 512 + (((cb & ~15) ^ ((rr & 7) << 4)) | (cb & 15));
    *(unsigned short*)((char*)h_bf + byt) = f2bf(v);
  }
  __syncthreads();

  const int ccol = lane & 15;
  const int crow = ((lane >> 4) << 2);     // 0,4,8,12
  const int q0 = w * 2;                    // rz ntile pair base
  const bool is_r = (w < 8);
  const int ctA0 = is_r ? q0 : q0 + 16;    // Xg ct for rz ([r|cand|z] col order)
  const int ctB  = 16 + w;                 // Xg ct for cand
  const f32x4* XgD = Xg + (size_t)dir * (chunkT * 4) * 48 * 64;
  unsigned short* sp_bf = dir ? sbw_bf : sfw_bf;
  const int coff = dir ? 256 : 0;
  // swizzled A-frag read address components (row = lane&15)
  const int ardbase = (lane & 15) * 512;
  const int arxor = ((lane & 7) << 4);
  const int afc = ((lane >> 4) << 4);

#pragma unroll 1
  for (int t = t0; t < t0 + chunkT; ++t) {
    const int tloc = t - t0;
    // issue all Xg loads for this step up front (cover L2/L3 latency under MFMA)
    const size_t rtb = ((size_t)(tloc * 4 + bx) * 48) * 64 + lane;
    f32x4 xa0 = XgD[rtb + (size_t)(ctA0 + 0) * 64];
    f32x4 xa1 = XgD[rtb + (size_t)(ctA0 + 1) * 64];
    f32x4 xb  = XgD[rtb + (size_t)ctB * 64];

    // ---------- phase A: rz = h @ Whrz (+x-part) ----------
    f32x4 accA0 = {}, accA1 = {};
#pragma unroll
    for (int kt = 0; kt < 8; ++kt) {
      int byt = ardbase + ((kt * 64 + afc) ^ arxor);
      bf16x8 a = *(const bf16x8*)((const char*)h_bf + byt);
      accA0 = __builtin_amdgcn_mfma_f32_16x16x32_bf16(a, wrz[0][kt], accA0, 0, 0, 0);
      accA1 = __builtin_amdgcn_mfma_f32_16x16x32_bf16(a, wrz[1][kt], accA1, 0, 0, 0);
    }
#pragma unroll
    for (int j = 0; j < 2; ++j) {
      f32x4 ac = j ? accA1 : accA0;
      f32x4 xv = j ? xa1 : xa0;
      int cl = (q0 + j) * 16 + ccol;       // rz col 0..511
#pragma unroll
      for (int r = 0; r < 4; ++r) {
        int rr = crow + r;
        float v = ac[r] + xv[r];
        float gate = __builtin_amdgcn_rcpf(1.0f + __builtin_amdgcn_exp2f(v)); // sigmoid
        if (is_r) {
          float h = h_f[rr * HPAD + cl];
          int cb = cl * 2;
          int byt = rr * 512 + (((cb & ~15) ^ ((rr & 7) << 4)) | (cb & 15));
          *(unsigned short*)((char*)rh_bf + byt) = f2bf(gate * h);
        } else {
          z_f[rr * HPAD + (cl - 256)] = gate;
        }
      }
    }
    asm volatile("s_waitcnt lgkmcnt(0)" ::: "memory");
    __builtin_amdgcn_s_barrier();

    // ---------- phase B: cand = tanh-form((r*h) @ Whc + x-part), update h ----------
    f32x4 accB = {};
#pragma unroll
    for (int kt = 0; kt < 8; ++kt) {
      int byt = ardbase + ((kt * 64 + afc) ^ arxor);
      bf16x8 a = *(const bf16x8*)((const char*)rh_bf + byt);
      accB = __builtin_amdgcn_mfma_f32_16x16x32_bf16(a, whcf[kt], accB, 0, 0, 0);
    }
    int gbase = (LAYER == 1 && dir) ? ((T_STEPS - 1 - t) * 64 + row0) : (t * 64 + row0);
    int c2 = w * 16 + ccol;                // cand col 0..255
#pragma unroll
    for (int r = 0; r < 4; ++r) {
      int rr = crow + r;
      float v = accB[r] + xb[r];
      float cand = __builtin_amdgcn_rcpf(1.0f + __builtin_amdgcn_exp2f(v)) * 2.0f - 1.0f;
      float z = z_f[rr * HPAD + c2];
      float h = h_f[rr * HPAD + c2];
      float hn = cand + z * (h - cand);
      h_f[rr * HPAD + c2] = hn;
      int cb = c2 * 2;
      int byt = rr * 512 + (((cb & ~15) ^ ((rr & 7) << 4)) | (cb & 15));
      *(unsigned short*)((char*)h_bf + byt) = f2bf(hn);
      if (LAYER == 0) sp_bf[(size_t)(gbase + rr) * 256 + c2] = f2bf(hn);
      else            out[(size_t)(gbase + rr) * 512 + coff + c2] = hn;
    }
    asm volatile("s_waitcnt lgkmcnt(0)" ::: "memory");
    __builtin_amdgcn_s_barrier();
  }

  // persist h; on last chunk also write fh/bh
  for (int i = tid; i < 16 * 256; i += 1024) {
    int rr = i >> 8, cc = i & 255;
    hst[i] = h_f[rr * HPAD + cc];
  }
  if (t0 + chunkT == T_STEPS) {
    float* dst = dout_h + (dir ? 32768 : 0) + (size_t)LAYER * 16384;
    for (int i = tid; i < 16 * 256; i += 1024) {
      int rr = i >> 8, cc = i & 255;
      dst[(size_t)(row0 + rr) * 256 + cc] = h_f[rr * HPAD + cc];
    }
  }
}

__global__ void diag_kernel(float* out, float v) { out[0] = v; }

// --------------------------------------------------------------------------------------
extern "C" void kernel_launch(void* const* d_in, const int* in_sizes, int n_in,
                              void* d_out, int out_size, void* d_ws, size_t ws_size,
                              hipStream_t stream) {
  const float* x     = (const float*)d_in[0];
  const float* fw_W0 = (const float*)d_in[2];
  const float* fw_b0 = (const float*)d_in[3];
  const float* fw_W1 = (const float*)d_in[4];
  const float* fw_b1 = (const float*)d_in[5];
  const float* bw_W0 = (const float*)d_in[6];
  const float* bw_b0 = (const float*)d_in[7];
  const float* bw_W1 = (const float*)d_in[8];
  const float* bw_b1 = (const float*)d_in[9];

  char* ws = (char*)d_ws;
  size_t off = 0;
  auto alloc = [&](size_t bytes) -> char* {
    char* p = ws + off; off += (bytes + 255) & ~(size_t)255; return p;
  };
  unsigned short* Wx0p  = (unsigned short*)alloc(2ull * 48 * 8 * 64 * 8 * 2);
  unsigned short* Wx1p  = (unsigned short*)alloc(2ull * 48 * 16 * 64 * 8 * 2);
  unsigned short* Whrz0 = (unsigned short*)alloc(2ull * 32 * 8 * 64 * 8 * 2);
  unsigned short* Whc0  = (unsigned short*)alloc(2ull * 16 * 8 * 64 * 8 * 2);
  unsigned short* Whrz1 = (unsigned short*)alloc(2ull * 32 * 8 * 64 * 8 * 2);
  unsigned short* Whc1  = (unsigned short*)alloc(2ull * 16 * 8 * 64 * 8 * 2);
  unsigned short* fs0   = (unsigned short*)alloc((size_t)TB * 256 * 2);
  unsigned short* bs0   = (unsigned short*)alloc((size_t)TB * 256 * 2);
  float* hstate         = (float*)alloc(2ull * 4 * 16 * 256 * 4);

  // pick largest time-chunk (<=128 for L3 residency) whose Xg buffer fits
  int chunkT = 0;
  for (int ct = 128; ct >= 8; ct >>= 1) {
    if (off + (size_t)ct * 2 * 64 * 768 * 4 <= ws_size) { chunkT = ct; break; }
  }
  float* out = (float*)d_out;
  if (chunkT == 0) {
    diag_kernel<<<1, 1, 0, stream>>>(out, 12345.0f);
    return;
  }
  f32x4* Xg = (f32x4*)alloc((size_t)chunkT * 2 * 64 * 768 * 4);
  float* dout_h = out + (size_t)TB * 512;

  auto packw = [&](const float* W, int rows, int kb, int ntl, int ktl, int mode, unsigned short* dst) {
    int total = ntl * ktl * 64;
    pack_w_kernel<<<(total + 255) / 256, 256, 0, stream>>>(W, rows, kb, ntl, ktl, mode, dst);
  };
  packw(fw_W0, 512, 0,   48, 8,  0, Wx0p);
  packw(bw_W0, 512, 0,   48, 8,  0, Wx0p + 48 * 8 * 64 * 8);
  packw(fw_W1, 768, 0,   48, 16, 0, Wx1p);
  packw(bw_W1, 768, 0,   48, 16, 0, Wx1p + 48 * 16 * 64 * 8);
  packw(fw_W0, 512, 256, 32, 8,  1, Whrz0);
  packw(bw_W0, 512, 256, 32, 8,  1, Whrz0 + 32 * 8 * 64 * 8);
  packw(fw_W0, 512, 256, 16, 8,  2, Whc0);
  packw(bw_W0, 512, 256, 16, 8,  2, Whc0 + 16 * 8 * 64 * 8);
  packw(fw_W1, 768, 512, 32, 8,  1, Whrz1);
  packw(bw_W1, 768, 512, 32, 8,  1, Whrz1 + 32 * 8 * 64 * 8);
  packw(fw_W1, 768, 512, 16, 8,  2, Whc1);
  packw(bw_W1, 768, 512, 16, 8,  2, Whc1 + 16 * 8 * 64 * 8);

  dim3 rgrid(4, 2);
  // layer 0
  for (int t0 = 0; t0 < T_STEPS; t0 += chunkT) {
    dim3 ggrid(chunkT / 2, 6, 2);
    gemm_xg_kernel<0><<<ggrid, 256, 0, stream>>>(x, nullptr, nullptr, Wx0p, fw_b0, bw_b0, Xg, t0, chunkT);
    gru_kernel<0><<<rgrid, 1024, 0, stream>>>(Xg,
        (const uint4*)Whrz0, (const uint4*)(Whrz0 + 32 * 8 * 64 * 8),
        (const uint4*)Whc0,  (const uint4*)(Whc0 + 16 * 8 * 64 * 8),
        fs0, bs0, nullptr, hstate, dout_h, t0, chunkT);
  }
  // layer 1
  for (int t0 = 0; t0 < T_STEPS; t0 += chunkT) {
    dim3 ggrid(chunkT / 2, 6, 2);
    gemm_xg_kernel<1><<<ggrid, 256, 0, stream>>>(nullptr, fs0, bs0, Wx1p, fw_b1, bw_b1, Xg, t0, chunkT);
    gru_kernel<1><<<rgrid, 1024, 0, stream>>>(Xg,
        (const uint4*)Whrz1, (const uint4*)(Whrz1 + 32 * 8 * 64 * 8),
        (const uint4*)Whc1,  (const uint4*)(Whc1 + 16 * 8 * 64 * 8),
        nullptr, nullptr, out, hstate, dout_h, t0, chunkT);
  }
}

// Round 5
// 5476.529 us; speedup vs baseline: 1.4366x; 1.4366x over previous
//
#include <hip/hip_runtime.h>
#include <hip/hip_bf16.h>

#define T_STEPS 512
#define BATCH 64
#define TB (T_STEPS * BATCH)   // 32768
#define HPAD 260

typedef short bf16x8 __attribute__((ext_vector_type(8)));
typedef float f32x4 __attribute__((ext_vector_type(4)));

union FragU { uint4 u; bf16x8 v; };

static __device__ __forceinline__ bf16x8 ld_frag(const uint4* p) {
  FragU f; f.u = *p; return f.v;
}

static __device__ __forceinline__ unsigned short f2bf(float f) {
  unsigned u = __float_as_uint(f);
  return (unsigned short)((u + 0x7FFFu + ((u >> 16) & 1u)) >> 16);
}

static __device__ __forceinline__ int revrow(int r) {
  int t = r >> 6, b = r & 63;
  return ((T_STEPS - 1 - t) << 6) | b;
}

#define S_RZ  (-1.4426950408889634f)   /* -log2(e)   : sigmoid(p)=1/(1+2^(S_RZ*p)) */
#define S_C   (-2.8853900817779268f)   /* -2*log2(e) : tanh(p)=2/(1+2^(S_C*p))-1   */

// ---------------- pack weights into MFMA B-fragment layout (with gate pre-scaling) ----
// modes: 0 = X3 (768 cols, order [r|cand|z], g=n>>8), 1 = RZ (512 cols, g=n<256?0:2), 2 = C (256 cols, g=1)
__global__ void pack_w_kernel(const float* __restrict__ W, int rows, int k_base,
                              int n_tiles, int k_tiles, int mode,
                              unsigned short* __restrict__ dst) {
  int gid = blockIdx.x * blockDim.x + threadIdx.x;
  int total = n_tiles * k_tiles * 64;
  if (gid >= total) return;
  int lane = gid & 63;
  int fi = gid >> 6;
  int kt = fi % k_tiles;
  int nt = fi / k_tiles;
  int n = nt * 16 + (lane & 15);
  int g, col; float s;
  if (mode == 0)      { g = n >> 8;            col = n & 255; s = (g == 1) ? S_C : S_RZ; }
  else if (mode == 1) { g = (n < 256) ? 0 : 2; col = n & 255; s = S_RZ; }
  else                { g = 1;                 col = n;       s = S_C; }
  int k0 = k_base + kt * 32 + ((lane >> 4) << 3);
  const float* src = W + ((size_t)g * rows + k0) * 256 + col;
  unsigned short v[8];
#pragma unroll
  for (int j = 0; j < 8; ++j) v[j] = f2bf(src[(size_t)j * 256] * s);
  uint4 o;
  o.x = v[0] | ((unsigned)v[1] << 16);
  o.y = v[2] | ((unsigned)v[3] << 16);
  o.z = v[4] | ((unsigned)v[5] << 16);
  o.w = v[6] | ((unsigned)v[7] << 16);
  ((uint4*)dst)[gid] = o;
}

static __device__ __forceinline__ bf16x8 cvt8(float4 f0, float4 f1) {
  uint4 o;
  o.x = f2bf(f0.x) | ((unsigned)f2bf(f0.y) << 16);
  o.y = f2bf(f0.z) | ((unsigned)f2bf(f0.w) << 16);
  o.z = f2bf(f1.x) | ((unsigned)f2bf(f1.y) << 16);
  o.w = f2bf(f1.z) | ((unsigned)f2bf(f1.w) << 16);
  FragU f; f.u = o; return f.v;
}

// ---------------- Xg GEMM (chunked): writes C-fragment tile layout --------------------
// Xg per dir: [rt = chunkT*4][ct = 48][lane = 64] f32x4  (16-row C tile per (rt,ct))
//   lane mapping: col = ct*16 + (lane&15), row_in_tile = (lane>>4)*4 + reg
template<int LAYER>
__global__ __launch_bounds__(256)
void gemm_xg_kernel(const float* __restrict__ x,
                    const unsigned short* __restrict__ fs0,
                    const unsigned short* __restrict__ bs0,
                    const unsigned short* __restrict__ Bp,
                    const float* __restrict__ bias_fw,
                    const float* __restrict__ bias_bw,
                    f32x4* __restrict__ Xg, int t0, int chunkT)
{
  constexpr int KT = (LAYER == 0) ? 8 : 16;
  int dir = blockIdx.z;
  int lane = threadIdx.x & 63;
  int w = threadIdx.x >> 6;
  int ww = w >> 1, wc = w & 1;
  int mt0 = blockIdx.x * 8 + ww * 4;
  int nt0 = blockIdx.y * 8 + wc * 4;
  const uint4* B = (const uint4*)Bp + (size_t)dir * 48 * KT * 64;
  const int arow = lane & 15;
  const int k0b = ((lane >> 4) << 3);

  f32x4 acc[4][4] = {};
#pragma unroll
  for (int kt = 0; kt < KT; ++kt) {
    int k0 = kt * 32 + k0b;
    bf16x8 a[4], b[4];
#pragma unroll
    for (int i = 0; i < 4; ++i) {
      int grow = t0 * 64 + (mt0 + i) * 16 + arow;
      if (LAYER == 0) {
        int gr = dir ? revrow(grow) : grow;
        const float4* s = (const float4*)(x + (size_t)gr * 256 + k0);
        a[i] = cvt8(s[0], s[1]);
      } else {
        const unsigned short* base; int r2 = grow, kk = k0;
        if (k0 < 256) { base = dir ? bs0 : fs0; }
        else          { base = dir ? fs0 : bs0; r2 = revrow(grow); kk = k0 - 256; }
        a[i] = *(const bf16x8*)(base + (size_t)r2 * 256 + kk);
      }
    }
#pragma unroll
    for (int j = 0; j < 4; ++j) b[j] = ld_frag(B + ((size_t)(nt0 + j) * KT + kt) * 64 + lane);
#pragma unroll
    for (int i = 0; i < 4; ++i)
#pragma unroll
      for (int j = 0; j < 4; ++j)
        acc[i][j] = __builtin_amdgcn_mfma_f32_16x16x32_bf16(a[i], b[j], acc[i][j], 0, 0, 0);
  }

  const float* bias = dir ? bias_bw : bias_fw;
  f32x4* C = Xg + (size_t)dir * (chunkT * 4) * 48 * 64;
#pragma unroll
  for (int j = 0; j < 4; ++j) {
    int ct = nt0 + j;
    int col = ct * 16 + (lane & 15);
    int g = col >> 8, cc = col & 255;
    float bv = ((g == 1) ? S_C : S_RZ) * bias[g * 256 + cc];
#pragma unroll
    for (int i = 0; i < 4; ++i) {
      int rt = blockIdx.x * 8 + ww * 4 + i;        // chunk-local 16-row tile index
      f32x4 v = acc[i][j];
      v[0] += bv; v[1] += bv; v[2] += bv; v[3] += bv;
      C[((size_t)rt * 48 + ct) * 64 + lane] = v;
    }
  }
}

// ---------------- persistent recurrent GRU kernel (one layer, both dirs, chunked) -----
// grid (4, 2): blockIdx.x = 16-row batch block, blockIdx.y = dir. 512 threads = 8 waves.
// amdgpu_waves_per_eu(2,2): pin exactly 2 waves/SIMD -> 256 VGPR/wave, no occupancy
// incentive for the allocator to spill the 192 VGPRs of resident weights.
template<int LAYER>
__global__ __launch_bounds__(512) __attribute__((amdgpu_waves_per_eu(2, 2)))
void gru_kernel(const f32x4* __restrict__ Xg,
                const uint4* __restrict__ whrz_fw, const uint4* __restrict__ whrz_bw, // [32][8][64]
                const uint4* __restrict__ whc_fw,  const uint4* __restrict__ whc_bw,  // [16][8][64]
                unsigned short* __restrict__ sfw_bf, unsigned short* __restrict__ sbw_bf,
                float* __restrict__ out,
                float* __restrict__ hstate, float* __restrict__ dout_h,
                int t0, int chunkT)
{
  const int dir = blockIdx.y;
  const int bx = blockIdx.x;
  const int row0 = bx * 16;
  const int tid = threadIdx.x;
  const int lane = tid & 63;
  const int w = tid >> 6;               // 0..7

  __shared__ __align__(16) unsigned short h_bf[16 * 256];   // swizzled bf16 h
  __shared__ __align__(16) unsigned short rh_bf[16 * 256];  // swizzled bf16 r*h
  __shared__ __align__(16) float h_f[16 * HPAD];            // fp32 h (padded stride)
  __shared__ __align__(16) float z_f[16 * HPAD];            // fp32 z gate

  const uint4* whrzp = dir ? whrz_bw : whrz_fw;
  const uint4* whcp  = dir ? whc_bw  : whc_fw;

  // resident weights: wave w owns rz ntiles w*4..w*4+3 and cand ntiles w*2, w*2+1 (192 VGPRs)
  bf16x8 wrz[4][8], whcf[2][8];
#pragma unroll
  for (int j = 0; j < 4; ++j)
#pragma unroll
    for (int kt = 0; kt < 8; ++kt)
      wrz[j][kt] = ld_frag(whrzp + ((size_t)(w * 4 + j) * 8 + kt) * 64 + lane);
#pragma unroll
  for (int j = 0; j < 2; ++j)
#pragma unroll
    for (int kt = 0; kt < 8; ++kt)
      whcf[j][kt] = ld_frag(whcp + ((size_t)(w * 2 + j) * 8 + kt) * 64 + lane);

  float* hst = hstate + (size_t)(dir * 4 + bx) * 4096;
  for (int i = tid; i < 16 * 256; i += 512) {
    float v = (t0 == 0) ? 0.0f : hst[i];
    int rr = i >> 8, cc = i & 255;
    h_f[rr * HPAD + cc] = v;
    int cb = cc * 2;
    int byt = rr * 512 + (((cb & ~15) ^ ((rr & 7) << 4)) | (cb & 15));
    *(unsigned short*)((char*)h_bf + byt) = f2bf(v);
  }
  __syncthreads();

  const int ccol = lane & 15;
  const int crow = ((lane >> 4) << 2);     // 0,4,8,12
  const int q0 = w * 4;                    // rz ntile base
  const bool is_r = (w < 4);
  const int ctA0 = is_r ? q0 : q0 + 16;    // Xg ct for rz ([r|cand|z] col order)
  const int ctB0 = 16 + w * 2;             // Xg ct for cand
  const f32x4* XgD = Xg + (size_t)dir * (chunkT * 4) * 48 * 64;
  unsigned short* sp_bf = dir ? sbw_bf : sfw_bf;
  const int coff = dir ? 256 : 0;
  // swizzled A-frag read address components (row = lane&15)
  const int ardbase = (lane & 15) * 512;
  const int arxor = ((lane & 7) << 4);
  const int afc = ((lane >> 4) << 4);

#pragma unroll 1
  for (int t = t0; t < t0 + chunkT; ++t) {
    const int tloc = t - t0;
    const size_t rtb = ((size_t)(tloc * 4 + bx) * 48) * 64 + lane;
    // phase-A Xg loads issued up front (cover L2/L3 latency under MFMA)
    f32x4 xa0 = XgD[rtb + (size_t)(ctA0 + 0) * 64];
    f32x4 xa1 = XgD[rtb + (size_t)(ctA0 + 1) * 64];
    f32x4 xa2 = XgD[rtb + (size_t)(ctA0 + 2) * 64];
    f32x4 xa3 = XgD[rtb + (size_t)(ctA0 + 3) * 64];

    // ---------- phase A: rz = h @ Whrz (+x-part) ----------
    f32x4 accA0 = {}, accA1 = {}, accA2 = {}, accA3 = {};
#pragma unroll
    for (int kt = 0; kt < 8; ++kt) {
      int byt = ardbase + ((kt * 64 + afc) ^ arxor);
      bf16x8 a = *(const bf16x8*)((const char*)h_bf + byt);
      accA0 = __builtin_amdgcn_mfma_f32_16x16x32_bf16(a, wrz[0][kt], accA0, 0, 0, 0);
      accA1 = __builtin_amdgcn_mfma_f32_16x16x32_bf16(a, wrz[1][kt], accA1, 0, 0, 0);
      accA2 = __builtin_amdgcn_mfma_f32_16x16x32_bf16(a, wrz[2][kt], accA2, 0, 0, 0);
      accA3 = __builtin_amdgcn_mfma_f32_16x16x32_bf16(a, wrz[3][kt], accA3, 0, 0, 0);
    }
#pragma unroll
    for (int j = 0; j < 4; ++j) {
      f32x4 ac = (j == 0) ? accA0 : (j == 1) ? accA1 : (j == 2) ? accA2 : accA3;
      f32x4 xv = (j == 0) ? xa0 : (j == 1) ? xa1 : (j == 2) ? xa2 : xa3;
      int cl = (q0 + j) * 16 + ccol;       // rz col 0..511
#pragma unroll
      for (int r = 0; r < 4; ++r) {
        int rr = crow + r;
        float v = ac[r] + xv[r];
        float gate = __builtin_amdgcn_rcpf(1.0f + __builtin_amdgcn_exp2f(v)); // sigmoid
        if (is_r) {
          float h = h_f[rr * HPAD + cl];
          int cb = cl * 2;
          int byt = rr * 512 + (((cb & ~15) ^ ((rr & 7) << 4)) | (cb & 15));
          *(unsigned short*)((char*)rh_bf + byt) = f2bf(gate * h);
        } else {
          z_f[rr * HPAD + (cl - 256)] = gate;
        }
      }
    }
    asm volatile("s_waitcnt lgkmcnt(0)" ::: "memory");
    __builtin_amdgcn_s_barrier();

    // ---------- phase B: cand = tanh-form((r*h) @ Whc + x-part), update h ----------
    f32x4 xb0 = XgD[rtb + (size_t)(ctB0 + 0) * 64];
    f32x4 xb1 = XgD[rtb + (size_t)(ctB0 + 1) * 64];
    f32x4 accB0 = {}, accB1 = {};
#pragma unroll
    for (int kt = 0; kt < 8; ++kt) {
      int byt = ardbase + ((kt * 64 + afc) ^ arxor);
      bf16x8 a = *(const bf16x8*)((const char*)rh_bf + byt);
      accB0 = __builtin_amdgcn_mfma_f32_16x16x32_bf16(a, whcf[0][kt], accB0, 0, 0, 0);
      accB1 = __builtin_amdgcn_mfma_f32_16x16x32_bf16(a, whcf[1][kt], accB1, 0, 0, 0);
    }
    int gbase = (LAYER == 1 && dir) ? ((T_STEPS - 1 - t) * 64 + row0) : (t * 64 + row0);
#pragma unroll
    for (int j = 0; j < 2; ++j) {
      f32x4 ac = j ? accB1 : accB0;
      f32x4 xv = j ? xb1 : xb0;
      int c2 = (w * 2 + j) * 16 + ccol;    // cand col 0..255
#pragma unroll
      for (int r = 0; r < 4; ++r) {
        int rr = crow + r;
        float v = ac[r] + xv[r];
        float cand = __builtin_amdgcn_rcpf(1.0f + __builtin_amdgcn_exp2f(v)) * 2.0f - 1.0f;
        float z = z_f[rr * HPAD + c2];
        float h = h_f[rr * HPAD + c2];
        float hn = cand + z * (h - cand);
        h_f[rr * HPAD + c2] = hn;
        int cb = c2 * 2;
        int byt = rr * 512 + (((cb & ~15) ^ ((rr & 7) << 4)) | (cb & 15));
        *(unsigned short*)((char*)h_bf + byt) = f2bf(hn);
        if (LAYER == 0) sp_bf[(size_t)(gbase + rr) * 256 + c2] = f2bf(hn);
        else            out[(size_t)(gbase + rr) * 512 + coff + c2] = hn;
      }
    }
    asm volatile("s_waitcnt lgkmcnt(0)" ::: "memory");
    __builtin_amdgcn_s_barrier();
  }

  // persist h; on last chunk also write fh/bh
  for (int i = tid; i < 16 * 256; i += 512) {
    int rr = i >> 8, cc = i & 255;
    hst[i] = h_f[rr * HPAD + cc];
  }
  if (t0 + chunkT == T_STEPS) {
    float* dst = dout_h + (dir ? 32768 : 0) + (size_t)LAYER * 16384;
    for (int i = tid; i < 16 * 256; i += 512) {
      int rr = i >> 8, cc = i & 255;
      dst[(size_t)(row0 + rr) * 256 + cc] = h_f[rr * HPAD + cc];
    }
  }
}

__global__ void diag_kernel(float* out, float v) { out[0] = v; }

// --------------------------------------------------------------------------------------
extern "C" void kernel_launch(void* const* d_in, const int* in_sizes, int n_in,
                              void* d_out, int out_size, void* d_ws, size_t ws_size,
                              hipStream_t stream) {
  const float* x     = (const float*)d_in[0];
  const float* fw_W0 = (const float*)d_in[2];
  const float* fw_b0 = (const float*)d_in[3];
  const float* fw_W1 = (const float*)d_in[4];
  const float* fw_b1 = (const float*)d_in[5];
  const float* bw_W0 = (const float*)d_in[6];
  const float* bw_b0 = (const float*)d_in[7];
  const float* bw_W1 = (const float*)d_in[8];
  const float* bw_b1 = (const float*)d_in[9];

  char* ws = (char*)d_ws;
  size_t off = 0;
  auto alloc = [&](size_t bytes) -> char* {
    char* p = ws + off; off += (bytes + 255) & ~(size_t)255; return p;
  };
  unsigned short* Wx0p  = (unsigned short*)alloc(2ull * 48 * 8 * 64 * 8 * 2);
  unsigned short* Wx1p  = (unsigned short*)alloc(2ull * 48 * 16 * 64 * 8 * 2);
  unsigned short* Whrz0 = (unsigned short*)alloc(2ull * 32 * 8 * 64 * 8 * 2);
  unsigned short* Whc0  = (unsigned short*)alloc(2ull * 16 * 8 * 64 * 8 * 2);
  unsigned short* Whrz1 = (unsigned short*)alloc(2ull * 32 * 8 * 64 * 8 * 2);
  unsigned short* Whc1  = (unsigned short*)alloc(2ull * 16 * 8 * 64 * 8 * 2);
  unsigned short* fs0   = (unsigned short*)alloc((size_t)TB * 256 * 2);
  unsigned short* bs0   = (unsigned short*)alloc((size_t)TB * 256 * 2);
  float* hstate         = (float*)alloc(2ull * 4 * 16 * 256 * 4);

  // pick largest time-chunk (<=128 for L3 residency) whose Xg buffer fits
  int chunkT = 0;
  for (int ct = 128; ct >= 8; ct >>= 1) {
    if (off + (size_t)ct * 2 * 64 * 768 * 4 <= ws_size) { chunkT = ct; break; }
  }
  float* out = (float*)d_out;
  if (chunkT == 0) {
    diag_kernel<<<1, 1, 0, stream>>>(out, 12345.0f);
    return;
  }
  f32x4* Xg = (f32x4*)alloc((size_t)chunkT * 2 * 64 * 768 * 4);
  float* dout_h = out + (size_t)TB * 512;

  auto packw = [&](const float* W, int rows, int kb, int ntl, int ktl, int mode, unsigned short* dst) {
    int total = ntl * ktl * 64;
    pack_w_kernel<<<(total + 255) / 256, 256, 0, stream>>>(W, rows, kb, ntl, ktl, mode, dst);
  };
  packw(fw_W0, 512, 0,   48, 8,  0, Wx0p);
  packw(bw_W0, 512, 0,   48, 8,  0, Wx0p + 48 * 8 * 64 * 8);
  packw(fw_W1, 768, 0,   48, 16, 0, Wx1p);
  packw(bw_W1, 768, 0,   48, 16, 0, Wx1p + 48 * 16 * 64 * 8);
  packw(fw_W0, 512, 256, 32, 8,  1, Whrz0);
  packw(bw_W0, 512, 256, 32, 8,  1, Whrz0 + 32 * 8 * 64 * 8);
  packw(fw_W0, 512, 256, 16, 8,  2, Whc0);
  packw(bw_W0, 512, 256, 16, 8,  2, Whc0 + 16 * 8 * 64 * 8);
  packw(fw_W1, 768, 512, 32, 8,  1, Whrz1);
  packw(bw_W1, 768, 512, 32, 8,  1, Whrz1 + 32 * 8 * 64 * 8);
  packw(fw_W1, 768, 512, 16, 8,  2, Whc1);
  packw(bw_W1, 768, 512, 16, 8,  2, Whc1 + 16 * 8 * 64 * 8);

  dim3 rgrid(4, 2);
  // layer 0
  for (int t0 = 0; t0 < T_STEPS; t0 += chunkT) {
    dim3 ggrid(chunkT / 2, 6, 2);
    gemm_xg_kernel<0><<<ggrid, 256, 0, stream>>>(x, nullptr, nullptr, Wx0p, fw_b0, bw_b0, Xg, t0, chunkT);
    gru_kernel<0><<<rgrid, 512, 0, stream>>>(Xg,
        (const uint4*)Whrz0, (const uint4*)(Whrz0 + 32 * 8 * 64 * 8),
        (const uint4*)Whc0,  (const uint4*)(Whc0 + 16 * 8 * 64 * 8),
        fs0, bs0, nullptr, hstate, dout_h, t0, chunkT);
  }
  // layer 1
  for (int t0 = 0; t0 < T_STEPS; t0 += chunkT) {
    dim3 ggrid(chunkT / 2, 6, 2);
    gemm_xg_kernel<1><<<ggrid, 256, 0, stream>>>(nullptr, fs0, bs0, Wx1p, fw_b1, bw_b1, Xg, t0, chunkT);
    gru_kernel<1><<<rgrid, 512, 0, stream>>>(Xg,
        (const uint4*)Whrz1, (const uint4*)(Whrz1 + 32 * 8 * 64 * 8),
        (const uint4*)Whc1,  (const uint4*)(Whc1 + 16 * 8 * 64 * 8),
        nullptr, nullptr, out, hstate, dout_h, t0, chunkT);
  }
}

// Round 7
// 4231.901 us; speedup vs baseline: 1.8591x; 1.2941x over previous
//
#include <hip/hip_runtime.h>
#include <hip/hip_bf16.h>

#define T_STEPS 512
#define BATCH 64
#define TB (T_STEPS * BATCH)   // 32768

typedef short bf16x8 __attribute__((ext_vector_type(8)));
typedef float f32x4 __attribute__((ext_vector_type(4)));

union FragU { uint4 u; bf16x8 v; };

static __device__ __forceinline__ bf16x8 ld_frag(const uint4* p) {
  FragU f; f.u = *p; return f.v;
}

static __device__ __forceinline__ unsigned short f2bf(float f) {
  unsigned u = __float_as_uint(f);
  return (unsigned short)((u + 0x7FFFu + ((u >> 16) & 1u)) >> 16);
}

static __device__ __forceinline__ int revrow(int r) {
  int t = r >> 6, b = r & 63;
  return ((T_STEPS - 1 - t) << 6) | b;
}

#define S_RZ  (-1.4426950408889634f)   /* -log2(e)   : sigmoid(p)=1/(1+2^(S_RZ*p)) */
#define S_C   (-2.8853900817779268f)   /* -2*log2(e) : tanh(p)=2/(1+2^(S_C*p))-1   */

// MFMA with B pinned to AGPR. Hazard discipline (CDNA manual wait states):
//  - MFMA_PIN1 (first MFMA of an acc chain after VALU zero-init): s_nop 1 covers
//    the VALU-write -> MFMA-read-SrcC requirement (2 slots).
//  - ACCFENCE before any VALU read of an MFMA D result: 2x s_nop 7 = 16 slots,
//    covering the 4-pass XDL write -> VALU read requirement with margin.
#define MFMA_PIN(acc, va, wa) \
  asm volatile("v_mfma_f32_16x16x32_bf16 %0, %1, %2, %0" \
               : "+v"(acc) : "v"(va), "a"(wa))
#define MFMA_PIN1(acc, va, wa) \
  asm volatile("s_nop 1\n\tv_mfma_f32_16x16x32_bf16 %0, %1, %2, %0" \
               : "+v"(acc) : "v"(va), "a"(wa))
#define ACCFENCE(acc) asm volatile("s_nop 7\n\ts_nop 7" : "+v"(acc))

// ---------------- pack weights into MFMA B-fragment layout (with gate pre-scaling) ----
// modes: 0 = X3 (768 cols, order [r|cand|z], g=n>>8), 1 = RZ (512 cols, g=n<256?0:2), 2 = C (256 cols, g=1)
__global__ void pack_w_kernel(const float* __restrict__ W, int rows, int k_base,
                              int n_tiles, int k_tiles, int mode,
                              unsigned short* __restrict__ dst) {
  int gid = blockIdx.x * blockDim.x + threadIdx.x;
  int total = n_tiles * k_tiles * 64;
  if (gid >= total) return;
  int lane = gid & 63;
  int fi = gid >> 6;
  int kt = fi % k_tiles;
  int nt = fi / k_tiles;
  int n = nt * 16 + (lane & 15);
  int g, col; float s;
  if (mode == 0)      { g = n >> 8;            col = n & 255; s = (g == 1) ? S_C : S_RZ; }
  else if (mode == 1) { g = (n < 256) ? 0 : 2; col = n & 255; s = S_RZ; }
  else                { g = 1;                 col = n;       s = S_C; }
  int k0 = k_base + kt * 32 + ((lane >> 4) << 3);
  const float* src = W + ((size_t)g * rows + k0) * 256 + col;
  unsigned short v[8];
#pragma unroll
  for (int j = 0; j < 8; ++j) v[j] = f2bf(src[(size_t)j * 256] * s);
  uint4 o;
  o.x = v[0] | ((unsigned)v[1] << 16);
  o.y = v[2] | ((unsigned)v[3] << 16);
  o.z = v[4] | ((unsigned)v[5] << 16);
  o.w = v[6] | ((unsigned)v[7] << 16);
  ((uint4*)dst)[gid] = o;
}

static __device__ __forceinline__ bf16x8 cvt8(float4 f0, float4 f1) {
  uint4 o;
  o.x = f2bf(f0.x) | ((unsigned)f2bf(f0.y) << 16);
  o.y = f2bf(f0.z) | ((unsigned)f2bf(f0.w) << 16);
  o.z = f2bf(f1.x) | ((unsigned)f2bf(f1.y) << 16);
  o.w = f2bf(f1.z) | ((unsigned)f2bf(f1.w) << 16);
  FragU f; f.u = o; return f.v;
}

// ---------------- Xg GEMM (chunked): writes C-fragment tile layout --------------------
// Xg per dir: [rt = chunkT*4][ct = 48][lane = 64] f32x4  (16-row C tile per (rt,ct))
template<int LAYER>
__global__ __launch_bounds__(256)
void gemm_xg_kernel(const float* __restrict__ x,
                    const unsigned short* __restrict__ fs0,
                    const unsigned short* __restrict__ bs0,
                    const unsigned short* __restrict__ Bp,
                    const float* __restrict__ bias_fw,
                    const float* __restrict__ bias_bw,
                    f32x4* __restrict__ Xg, int t0, int chunkT)
{
  constexpr int KT = (LAYER == 0) ? 8 : 16;
  int dir = blockIdx.z;
  int lane = threadIdx.x & 63;
  int w = threadIdx.x >> 6;
  int ww = w >> 1, wc = w & 1;
  int mt0 = blockIdx.x * 8 + ww * 4;
  int nt0 = blockIdx.y * 8 + wc * 4;
  const uint4* B = (const uint4*)Bp + (size_t)dir * 48 * KT * 64;
  const int arow = lane & 15;
  const int k0b = ((lane >> 4) << 3);

  f32x4 acc[4][4] = {};
#pragma unroll
  for (int kt = 0; kt < KT; ++kt) {
    int k0 = kt * 32 + k0b;
    bf16x8 a[4], b[4];
#pragma unroll
    for (int i = 0; i < 4; ++i) {
      int grow = t0 * 64 + (mt0 + i) * 16 + arow;
      if (LAYER == 0) {
        int gr = dir ? revrow(grow) : grow;
        const float4* s = (const float4*)(x + (size_t)gr * 256 + k0);
        a[i] = cvt8(s[0], s[1]);
      } else {
        const unsigned short* base; int r2 = grow, kk = k0;
        if (k0 < 256) { base = dir ? bs0 : fs0; }
        else          { base = dir ? fs0 : bs0; r2 = revrow(grow); kk = k0 - 256; }
        a[i] = *(const bf16x8*)(base + (size_t)r2 * 256 + kk);
      }
    }
#pragma unroll
    for (int j = 0; j < 4; ++j) b[j] = ld_frag(B + ((size_t)(nt0 + j) * KT + kt) * 64 + lane);
#pragma unroll
    for (int i = 0; i < 4; ++i)
#pragma unroll
      for (int j = 0; j < 4; ++j)
        acc[i][j] = __builtin_amdgcn_mfma_f32_16x16x32_bf16(a[i], b[j], acc[i][j], 0, 0, 0);
  }

  const float* bias = dir ? bias_bw : bias_fw;
  f32x4* C = Xg + (size_t)dir * (chunkT * 4) * 48 * 64;
#pragma unroll
  for (int j = 0; j < 4; ++j) {
    int ct = nt0 + j;
    int col = ct * 16 + (lane & 15);
    int g = col >> 8, cc = col & 255;
    float bv = ((g == 1) ? S_C : S_RZ) * bias[g * 256 + cc];
#pragma unroll
    for (int i = 0; i < 4; ++i) {
      int rt = blockIdx.x * 8 + ww * 4 + i;
      f32x4 v = acc[i][j];
      v[0] += bv; v[1] += bv; v[2] += bv; v[3] += bv;
      C[((size_t)rt * 48 + ct) * 64 + lane] = v;
    }
  }
}

// ---------------- persistent recurrent GRU kernel (one layer, both dirs, chunked) -----
// grid (4, 2): blockIdx.x = 16-row batch block, blockIdx.y = dir. 512 threads = 8 waves.
// Whrz: 128 regs/wave pinned in AGPRs (asm "a"); Whc: 128 KB in LDS (intrinsic MFMA).
// fp32 h: 8 regs/wave (each wave owns its 32 cand cols). Total/wave ~233 <= 256.
template<int LAYER>
__global__ __launch_bounds__(512) __attribute__((amdgpu_waves_per_eu(2, 2)))
void gru_kernel(const f32x4* __restrict__ Xg,
                const uint4* __restrict__ whrz_fw, const uint4* __restrict__ whrz_bw, // [32][8][64]
                const uint4* __restrict__ whc_fw,  const uint4* __restrict__ whc_bw,  // [16][8][64]
                unsigned short* __restrict__ sfw_bf, unsigned short* __restrict__ sbw_bf,
                float* __restrict__ out,
                float* __restrict__ hstate, float* __restrict__ dout_h,
                int t0, int chunkT)
{
  const int dir = blockIdx.y;
  const int bx = blockIdx.x;
  const int row0 = bx * 16;
  const int tid = threadIdx.x;
  const int lane = tid & 63;
  const int w = tid >> 6;               // 0..7

  __shared__ __align__(16) unsigned short h_bf[16 * 256];   // swizzled bf16 h       (8 KB)
  __shared__ __align__(16) unsigned short rh_bf[16 * 256];  // swizzled bf16 r*h     (8 KB)
  __shared__ __align__(16) unsigned short z_h[16 * 256];    // fp16 z gate           (8 KB)
  __shared__ __align__(16) uint4 wc_lds[16 * 8 * 64];       // Whc B-fragments     (128 KB)

  const uint4* whrzp = dir ? whrz_bw : whrz_fw;
  const uint4* whcp  = dir ? whc_bw  : whc_fw;

  // stage Whc into LDS (one-time per dispatch)
  for (int i = tid; i < 16 * 8 * 64; i += 512) wc_lds[i] = whcp[i];

  // Whrz fragments: wave w owns rz ntiles w*4..w*4+3; only asm "a" uses -> AGPRs.
  bf16x8 wrz[4][8];
#pragma unroll
  for (int j = 0; j < 4; ++j)
#pragma unroll
    for (int kt = 0; kt < 8; ++kt)
      wrz[j][kt] = ld_frag(whrzp + ((size_t)(w * 4 + j) * 8 + kt) * 64 + lane);

  const int ccol = lane & 15;
  const int crow = ((lane >> 4) << 2);     // 0,4,8,12

  float* hst = hstate + (size_t)(dir * 4 + bx) * 4096;
  // init swizzled bf16 h (all 16x256)
  for (int i = tid; i < 16 * 256; i += 512) {
    float v = (t0 == 0) ? 0.0f : hst[i];
    int rr = i >> 8, cc = i & 255;
    int cb = cc * 2;
    int byt = rr * 512 + (((cb & ~15) ^ ((rr & 7) << 4)) | (cb & 15));
    *(unsigned short*)((char*)h_bf + byt) = f2bf(v);
  }
  // init register-resident fp32 h: wave w owns cand cols [32w, 32w+32)
  float hreg[2][4];
#pragma unroll
  for (int j = 0; j < 2; ++j)
#pragma unroll
    for (int r = 0; r < 4; ++r) {
      int rr = crow + r, c = (w * 2 + j) * 16 + ccol;
      hreg[j][r] = (t0 == 0) ? 0.0f : hst[rr * 256 + c];
    }
  __syncthreads();

  const int q0 = w * 4;                    // rz ntile base
  const bool is_r = (w < 4);
  const int ctA0 = is_r ? q0 : q0 + 16;    // Xg ct for rz ([r|cand|z] col order)
  const int ctB0 = 16 + w * 2;             // Xg ct for cand
  const f32x4* XgD = Xg + (size_t)dir * (chunkT * 4) * 48 * 64;
  unsigned short* sp_bf = dir ? sbw_bf : sfw_bf;
  const int coff = dir ? 256 : 0;
  // swizzled A-frag read address components (row = lane&15)
  const int ardbase = (lane & 15) * 512;
  const int arxor = ((lane & 7) << 4);
  const int afc = ((lane >> 4) << 4);

#pragma unroll 1
  for (int t = t0; t < t0 + chunkT; ++t) {
    const int tloc = t - t0;
    const size_t rtb = ((size_t)(tloc * 4 + bx) * 48) * 64 + lane;
    f32x4 xa0 = XgD[rtb + (size_t)(ctA0 + 0) * 64];
    f32x4 xa1 = XgD[rtb + (size_t)(ctA0 + 1) * 64];
    f32x4 xa2 = XgD[rtb + (size_t)(ctA0 + 2) * 64];
    f32x4 xa3 = XgD[rtb + (size_t)(ctA0 + 3) * 64];

    // ---------- phase A: rz = h @ Whrz (+x-part), weights from AGPR ----------
    f32x4 accA0 = {}, accA1 = {}, accA2 = {}, accA3 = {};
    {
      int byt = ardbase + ((0 * 64 + afc) ^ arxor);
      bf16x8 a = *(const bf16x8*)((const char*)h_bf + byt);
      MFMA_PIN1(accA0, a, wrz[0][0]);
      MFMA_PIN1(accA1, a, wrz[1][0]);
      MFMA_PIN1(accA2, a, wrz[2][0]);
      MFMA_PIN1(accA3, a, wrz[3][0]);
    }
#pragma unroll
    for (int kt = 1; kt < 8; ++kt) {
      int byt = ardbase + ((kt * 64 + afc) ^ arxor);
      bf16x8 a = *(const bf16x8*)((const char*)h_bf + byt);
      MFMA_PIN(accA0, a, wrz[0][kt]);
      MFMA_PIN(accA1, a, wrz[1][kt]);
      MFMA_PIN(accA2, a, wrz[2][kt]);
      MFMA_PIN(accA3, a, wrz[3][kt]);
    }
    ACCFENCE(accA0); ACCFENCE(accA1); ACCFENCE(accA2); ACCFENCE(accA3);
#pragma unroll
    for (int j = 0; j < 4; ++j) {
      f32x4 ac = (j == 0) ? accA0 : (j == 1) ? accA1 : (j == 2) ? accA2 : accA3;
      f32x4 xv = (j == 0) ? xa0 : (j == 1) ? xa1 : (j == 2) ? xa2 : xa3;
      int cl = (q0 + j) * 16 + ccol;       // rz col 0..511
#pragma unroll
      for (int r = 0; r < 4; ++r) {
        int rr = crow + r;
        float v = ac[r] + xv[r];
        float gate = __builtin_amdgcn_rcpf(1.0f + __builtin_amdgcn_exp2f(v)); // sigmoid
        if (is_r) {
          int cb = cl * 2;
          int byt = rr * 512 + (((cb & ~15) ^ ((rr & 7) << 4)) | (cb & 15));
          unsigned short hu = *(const unsigned short*)((const char*)h_bf + byt);
          float h = __uint_as_float((unsigned)hu << 16);
          *(unsigned short*)((char*)rh_bf + byt) = f2bf(gate * h);
        } else {
          _Float16 zh = (_Float16)gate;
          z_h[rr * 256 + (cl - 256)] = __builtin_bit_cast(unsigned short, zh);
        }
      }
    }
    asm volatile("s_waitcnt lgkmcnt(0)" ::: "memory");
    __builtin_amdgcn_s_barrier();

    // ---------- phase B: cand = tanh-form((r*h) @ Whc + x-part), update h ----------
    f32x4 xb0 = XgD[rtb + (size_t)(ctB0 + 0) * 64];
    f32x4 xb1 = XgD[rtb + (size_t)(ctB0 + 1) * 64];
    f32x4 accB0 = {}, accB1 = {};
#pragma unroll
    for (int kt = 0; kt < 8; ++kt) {
      int byt = ardbase + ((kt * 64 + afc) ^ arxor);
      bf16x8 a = *(const bf16x8*)((const char*)rh_bf + byt);
      bf16x8 b0 = *(const bf16x8*)&wc_lds[((size_t)(w * 2 + 0) * 8 + kt) * 64 + lane];
      bf16x8 b1 = *(const bf16x8*)&wc_lds[((size_t)(w * 2 + 1) * 8 + kt) * 64 + lane];
      accB0 = __builtin_amdgcn_mfma_f32_16x16x32_bf16(a, b0, accB0, 0, 0, 0);
      accB1 = __builtin_amdgcn_mfma_f32_16x16x32_bf16(a, b1, accB1, 0, 0, 0);
    }
    int gbase = (LAYER == 1 && dir) ? ((T_STEPS - 1 - t) * 64 + row0) : (t * 64 + row0);
#pragma unroll
    for (int j = 0; j < 2; ++j) {
      f32x4 ac = j ? accB1 : accB0;
      f32x4 xv = j ? xb1 : xb0;
      int c2 = (w * 2 + j) * 16 + ccol;    // cand col 0..255
#pragma unroll
      for (int r = 0; r < 4; ++r) {
        int rr = crow + r;
        float v = ac[r] + xv[r];
        float cand = __builtin_amdgcn_rcpf(1.0f + __builtin_amdgcn_exp2f(v)) * 2.0f - 1.0f;
        _Float16 zh = __builtin_bit_cast(_Float16, z_h[rr * 256 + c2]);
        float z = (float)zh;
        float h = hreg[j][r];
        float hn = cand + z * (h - cand);
        hreg[j][r] = hn;
        int cb = c2 * 2;
        int byt = rr * 512 + (((cb & ~15) ^ ((rr & 7) << 4)) | (cb & 15));
        *(unsigned short*)((char*)h_bf + byt) = f2bf(hn);
        if (LAYER == 0) sp_bf[(size_t)(gbase + rr) * 256 + c2] = f2bf(hn);
        else            out[(size_t)(gbase + rr) * 512 + coff + c2] = hn;
      }
    }
    asm volatile("s_waitcnt lgkmcnt(0)" ::: "memory");
    __builtin_amdgcn_s_barrier();
  }

  // persist h (each wave writes its own cand cols); on last chunk also write fh/bh
#pragma unroll
  for (int j = 0; j < 2; ++j)
#pragma unroll
    for (int r = 0; r < 4; ++r) {
      int rr = crow + r, c = (w * 2 + j) * 16 + ccol;
      hst[rr * 256 + c] = hreg[j][r];
      if (t0 + chunkT == T_STEPS) {
        float* dst = dout_h + (dir ? 32768 : 0) + (size_t)LAYER * 16384;
        dst[(size_t)(row0 + rr) * 256 + c] = hreg[j][r];
      }
    }
}

__global__ void diag_kernel(float* out, float v) { out[0] = v; }

// --------------------------------------------------------------------------------------
extern "C" void kernel_launch(void* const* d_in, const int* in_sizes, int n_in,
                              void* d_out, int out_size, void* d_ws, size_t ws_size,
                              hipStream_t stream) {
  const float* x     = (const float*)d_in[0];
  const float* fw_W0 = (const float*)d_in[2];
  const float* fw_b0 = (const float*)d_in[3];
  const float* fw_W1 = (const float*)d_in[4];
  const float* fw_b1 = (const float*)d_in[5];
  const float* bw_W0 = (const float*)d_in[6];
  const float* bw_b0 = (const float*)d_in[7];
  const float* bw_W1 = (const float*)d_in[8];
  const float* bw_b1 = (const float*)d_in[9];

  char* ws = (char*)d_ws;
  size_t off = 0;
  auto alloc = [&](size_t bytes) -> char* {
    char* p = ws + off; off += (bytes + 255) & ~(size_t)255; return p;
  };
  unsigned short* Wx0p  = (unsigned short*)alloc(2ull * 48 * 8 * 64 * 8 * 2);
  unsigned short* Wx1p  = (unsigned short*)alloc(2ull * 48 * 16 * 64 * 8 * 2);
  unsigned short* Whrz0 = (unsigned short*)alloc(2ull * 32 * 8 * 64 * 8 * 2);
  unsigned short* Whc0  = (unsigned short*)alloc(2ull * 16 * 8 * 64 * 8 * 2);
  unsigned short* Whrz1 = (unsigned short*)alloc(2ull * 32 * 8 * 64 * 8 * 2);
  unsigned short* Whc1  = (unsigned short*)alloc(2ull * 16 * 8 * 64 * 8 * 2);
  unsigned short* fs0   = (unsigned short*)alloc((size_t)TB * 256 * 2);
  unsigned short* bs0   = (unsigned short*)alloc((size_t)TB * 256 * 2);
  float* hstate         = (float*)alloc(2ull * 4 * 16 * 256 * 4);

  int chunkT = 0;
  for (int ct = 128; ct >= 8; ct >>= 1) {
    if (off + (size_t)ct * 2 * 64 * 768 * 4 <= ws_size) { chunkT = ct; break; }
  }
  float* out = (float*)d_out;
  if (chunkT == 0) {
    diag_kernel<<<1, 1, 0, stream>>>(out, 12345.0f);
    return;
  }
  f32x4* Xg = (f32x4*)alloc((size_t)chunkT * 2 * 64 * 768 * 4);
  float* dout_h = out + (size_t)TB * 512;

  auto packw = [&](const float* W, int rows, int kb, int ntl, int ktl, int mode, unsigned short* dst) {
    int total = ntl * ktl * 64;
    pack_w_kernel<<<(total + 255) / 256, 256, 0, stream>>>(W, rows, kb, ntl, ktl, mode, dst);
  };
  packw(fw_W0, 512, 0,   48, 8,  0, Wx0p);
  packw(bw_W0, 512, 0,   48, 8,  0, Wx0p + 48 * 8 * 64 * 8);
  packw(fw_W1, 768, 0,   48, 16, 0, Wx1p);
  packw(bw_W1, 768, 0,   48, 16, 0, Wx1p + 48 * 16 * 64 * 8);
  packw(fw_W0, 512, 256, 32, 8,  1, Whrz0);
  packw(bw_W0, 512, 256, 32, 8,  1, Whrz0 + 32 * 8 * 64 * 8);
  packw(fw_W0, 512, 256, 16, 8,  2, Whc0);
  packw(bw_W0, 512, 256, 16, 8,  2, Whc0 + 16 * 8 * 64 * 8);
  packw(fw_W1, 768, 512, 32, 8,  1, Whrz1);
  packw(bw_W1, 768, 512, 32, 8,  1, Whrz1 + 32 * 8 * 64 * 8);
  packw(fw_W1, 768, 512, 16, 8,  2, Whc1);
  packw(bw_W1, 768, 512, 16, 8,  2, Whc1 + 16 * 8 * 64 * 8);

  dim3 rgrid(4, 2);
  // layer 0
  for (int t0 = 0; t0 < T_STEPS; t0 += chunkT) {
    dim3 ggrid(chunkT / 2, 6, 2);
    gemm_xg_kernel<0><<<ggrid, 256, 0, stream>>>(x, nullptr, nullptr, Wx0p, fw_b0, bw_b0, Xg, t0, chunkT);
    gru_kernel<0><<<rgrid, 512, 0, stream>>>(Xg,
        (const uint4*)Whrz0, (const uint4*)(Whrz0 + 32 * 8 * 64 * 8),
        (const uint4*)Whc0,  (const uint4*)(Whc0 + 16 * 8 * 64 * 8),
        fs0, bs0, nullptr, hstate, dout_h, t0, chunkT);
  }
  // layer 1
  for (int t0 = 0; t0 < T_STEPS; t0 += chunkT) {
    dim3 ggrid(chunkT / 2, 6, 2);
    gemm_xg_kernel<1><<<ggrid, 256, 0, stream>>>(nullptr, fs0, bs0, Wx1p, fw_b1, bw_b1, Xg, t0, chunkT);
    gru_kernel<1><<<rgrid, 512, 0, stream>>>(Xg,
        (const uint4*)Whrz1, (const uint4*)(Whrz1 + 32 * 8 * 64 * 8),
        (const uint4*)Whc1,  (const uint4*)(Whc1 + 16 * 8 * 64 * 8),
        nullptr, nullptr, out, hstate, dout_h, t0, chunkT);
  }
}